// Round 7
// baseline (168.996 us; speedup 1.0000x reference)
//
#include <hip/hip_runtime.h>
#include <math.h>

#define NB 8
#define HH 256
#define WW 256
#define HW (HH*WW)

// ---- workspace layout (BYTE offsets) ----
#define OFF_AFFB  0UL                 // [8][8][256][256] bf16 (8388608 B)
#define OFF_W1FB  8388608UL           // [6][2][64][8] bf16 frag order (12288 B)
#define OFF_B1FB  8400896UL           // [32] fp32
#define OFF_W2FB  8401024UL           // [9][4][64][8] bf16 B-frag order (36864 B)
#define OFF_B2FB  8437888UL           // [64] fp32
#define OFF_W3FB  8438144UL           // [2][64][8] bf16 B-frag order (2048 B)

typedef short  short8 __attribute__((ext_vector_type(8)));
typedef ushort u16x8  __attribute__((ext_vector_type(8)));
typedef ushort u16x4  __attribute__((ext_vector_type(4)));
typedef float  f32x4  __attribute__((ext_vector_type(4)));

__device__ __forceinline__ ushort f2bf(float x) {
  uint u = __float_as_uint(x);
  return (ushort)((u + 0x7FFFu + ((u >> 16) & 1u)) >> 16);
}
__device__ __forceinline__ float bf2f(ushort h) {
  uint u = ((uint)h) << 16;
  return __uint_as_float(u);
}

// ---------------- prep: fold BN into bf16 MFMA fragment-order weights ----------------
__global__ __launch_bounds__(256) void prep_weights(
    const float* __restrict__ w1, const float* __restrict__ g1,
    const float* __restrict__ b1, const float* __restrict__ m1,
    const float* __restrict__ v1,
    const float* __restrict__ w2, const float* __restrict__ g2,
    const float* __restrict__ b2, const float* __restrict__ m2,
    const float* __restrict__ v2, const float* __restrict__ w3,
    char* __restrict__ wsb) {
  int idx = blockIdx.x * 256 + threadIdx.x;
  ushort* w1f = (ushort*)(wsb + OFF_W1FB);
  float* b1f  = (float*)(wsb + OFF_B1FB);
  ushort* w2f = (ushort*)(wsb + OFF_W2FB);
  float* b2f  = (float*)(wsb + OFF_B2FB);
  ushort* w3f = (ushort*)(wsb + OFF_W3FB);
  if (idx < 6144) {
    // idx = ((s*2+nt)*64 + lane)*8 + jj ; s = ky*2+t; B-operand: n=outch, k=2px*16ch
    int jj = idx & 7;
    int lane = (idx >> 3) & 63;
    int nt = (idx >> 9) & 1;
    int s = idx >> 10;
    int ky = s >> 1, t = s & 1;
    int q = lane >> 4, lx = lane & 15;
    int k = q * 8 + jj;
    int dcol = k >> 4, ch = k & 15;
    int kx = t * 2 + dcol;
    int out = nt * 16 + lx;
    float inv = g1[out] / sqrtf(v1[out] + 1e-5f);
    float val = (ch < 12 && kx < 3) ? w1[((out * 12 + ch) * 3 + ky) * 3 + kx] * inv : 0.f;
    w1f[idx] = f2bf(val);
  }
  int j = idx - 6144;
  if (j >= 0 && j < 18432) {
    int kk   = j >> 11;
    int nt   = (j >> 9) & 3;
    int lane = (j >> 3) & 63;
    int jj   = j & 7;
    int q  = lane >> 4, lx = lane & 15;
    int cin = q * 8 + jj;
    int out = nt * 16 + lx;
    float inv = g2[out] / sqrtf(v2[out] + 1e-5f);
    w2f[j] = f2bf(w2[(out * 32 + cin) * 9 + kk] * inv);
    if (kk == 0 && q == 0 && jj == 0) b2f[out] = b2[out] - m2[out] * inv;
  }
  int k2 = idx - 24576;
  if (k2 >= 0 && k2 < 32) {
    float inv = g1[k2] / sqrtf(v1[k2] + 1e-5f);
    b1f[k2] = b1[k2] - m1[k2] * inv;
  }
  int k3 = idx - 24608;
  if (k3 >= 0 && k3 < 1024) {
    int jj = k3 & 7;
    int lane = (k3 >> 3) & 63;
    int slice = k3 >> 9;
    int q = lane >> 4, lx = lane & 15;
    int ch = slice * 32 + q * 8 + jj;
    w3f[k3] = (lx < 8) ? f2bf(w3[lx * 64 + ch]) : (ushort)0;
  }
}

// ---------------- trunk: feats (inline, 20x20 halo) + conv1 + conv2 + conv3 ----------------
// LDS: buf[0..6464) ushorts = 808 16B chunks: feats tile [20][20][16ch], XOR-swizzled
//      buf[6464..18128) = x1 tile [18*18][36] (px stride 36 = pad)
//      relayout phase overlays buf[0..17408) after conv2 MFMA completes
__global__ __launch_bounds__(256) void trunk_kernel(
    const float* __restrict__ normal, const float* __restrict__ left,
    const float* __restrict__ right, const float* __restrict__ disp,
    char* __restrict__ wsb) {
  __shared__ ushort buf[18304];  // 36608 B
  ushort* x1t = buf + 6464;
  const short8* __restrict__ w1fv = (const short8*)(wsb + OFF_W1FB);
  const float* __restrict__ b1f = (const float*)(wsb + OFF_B1FB);
  const short8* __restrict__ w2fv = (const short8*)(wsb + OFF_W2FB);
  const float* __restrict__ b2f = (const float*)(wsb + OFF_B2FB);
  const short8* __restrict__ w3fv = (const short8*)(wsb + OFF_W3FB);
  ushort* aff = (ushort*)(wsb + OFF_AFFB);

  int blk = blockIdx.x;
  int n = blk >> 8;
  int t = blk & 255;
  int ty0 = (t >> 4) << 4;
  int tx0 = (t & 15) << 4;
  int tid = threadIdx.x;
  int lane = tid & 63;
  int wid = tid >> 6;
  int q = lane >> 4;
  int lx = lane & 15;

  // ---- phase 1: feats for 20x20 halo region -> LDS (swizzled chunks) ----
  if (tid < 8) *(u16x8*)&buf[(800 + tid) * 8] = (u16x8)0;  // overflow slots
  for (int e = tid; e < 400; e += 256) {
    int row = e / 20, col = e - row * 20;
    int gy = ty0 + row - 2, gx = tx0 + col - 2;
    ushort tmp[16];
#pragma unroll
    for (int c = 12; c < 16; ++c) tmp[c] = 0;
    if (gy >= 0 && gy < HH && gx >= 0 && gx < WW) {
#pragma unroll
      for (int c = 0; c < 3; ++c)
        tmp[c] = f2bf(normal[(size_t)(n * 3 + c) * HW + gy * WW + gx]);
      int i2 = gy << 1, j2 = gx << 1;
      float cl[3];
#pragma unroll
      for (int c = 0; c < 3; ++c) {
        const float* Lp = left + ((size_t)(n * 3 + c) * 512 + i2) * 512 + j2;
        float2 a0 = *(const float2*)Lp;
        float2 a1 = *(const float2*)(Lp + 512);
        cl[c] = 0.25f * (a0.x + a0.y + a1.x + a1.y);
        tmp[3 + c] = f2bf(cl[c]);
        const float* Rp = right + ((size_t)(n * 3 + c) * 512 + i2) * 512 + j2;
        float2 b0 = *(const float2*)Rp;
        float2 b1v = *(const float2*)(Rp + 512);
        tmp[6 + c] = f2bf(0.25f * (b0.x + b0.y + b1v.x + b1v.y));
      }
      float d = disp[(size_t)n * HW + gy * WW + gx];
      float xs = (float)gx - d;
      float x0f = floorf(xs);
      float fr = xs - x0f;
      int ix0 = (int)x0f;
      int ix1 = ix0 + 1;
      float vm0 = (ix0 >= 0 && ix0 < WW) ? 1.f : 0.f;
      float vm1 = (ix1 >= 0 && ix1 < WW) ? 1.f : 0.f;
      int x0c = min(max(ix0, 0), WW - 1);
      int x1c = min(max(ix1, 0), WW - 1);
      bool adj = (x1c == x0c + 1);
      int xs2 = min(x0c + 1, WW - 1);
#pragma unroll
      for (int c = 0; c < 3; ++c) {
        const float* Rb = right + ((size_t)(n * 3 + c) * 512 + i2) * 512;
        float2 f0 = *(const float2*)(Rb + (x0c << 1));
        float2 f1 = *(const float2*)(Rb + (x0c << 1) + 512);
        float2 f2v = *(const float2*)(Rb + (xs2 << 1));
        float2 f3 = *(const float2*)(Rb + (xs2 << 1) + 512);
        float avg0 = 0.25f * (f0.x + f0.y + f1.x + f1.y);
        float avg1 = 0.25f * (f2v.x + f2v.y + f3.x + f3.y);
        float gg0 = avg0 * vm0;
        float gg1 = (adj ? avg1 : avg0) * vm1;
        float warped = gg0 * (1.f - fr) + gg1 * fr;
        tmp[9 + c] = f2bf(fabsf(cl[c] - warped));
      }
    } else {
#pragma unroll
      for (int c = 0; c < 12; ++c) tmp[c] = 0;
    }
    int G0 = e * 2, G1 = G0 + 1;
    int s0 = G0 ^ ((G0 >> 3) & 7);
    int s1 = G1 ^ ((G1 >> 3) & 7);
    *(u16x8*)&buf[s0 * 8] = *(u16x8*)&tmp[0];
    *(u16x8*)&buf[s1 * 8] = *(u16x8*)&tmp[8];
  }
  __syncthreads();

  // ---- phase 2: conv1 MFMA over 18x18 halo outputs; A=pixels, B=weights ----
  {
    short8 bw1[6][2];
#pragma unroll
    for (int s = 0; s < 6; ++s)
#pragma unroll
      for (int nt = 0; nt < 2; ++nt) bw1[s][nt] = w1fv[(s * 2 + nt) * 64 + lane];
    float bias1[2] = {b1f[lx], b1f[16 + lx]};
    for (int m = wid; m < 21; m += 4) {
      int pidx = min(m * 16 + lx, 323);
      int oyr = pidx / 18, oxr = pidx - oyr * 18;  // staged out coords 0..17
      f32x4 a1[2];
      a1[0] = (f32x4)0.f; a1[1] = (f32x4)0.f;
#pragma unroll
      for (int s = 0; s < 6; ++s) {
        int ky = s >> 1, tt = s & 1;
        int G = ((oyr + ky) * 20 + oxr + tt * 2 + (q >> 1)) * 2 + (q & 1);
        int slot = G ^ ((G >> 3) & 7);
        short8 a = *(const short8*)&buf[slot * 8];
        a1[0] = __builtin_amdgcn_mfma_f32_16x16x32_bf16(a, bw1[s][0], a1[0], 0, 0, 0);
        a1[1] = __builtin_amdgcn_mfma_f32_16x16x32_bf16(a, bw1[s][1], a1[1], 0, 0, 0);
      }
      // D: row(q*4+r) = px-in-tile, col(lx) = outch
#pragma unroll
      for (int r = 0; r < 4; ++r) {
        int p2 = m * 16 + q * 4 + r;
        if (p2 < 324) {
          int ry = p2 / 18, rx = p2 - ry * 18;
          int gy = ty0 + ry - 1, gx = tx0 + rx - 1;
          bool okp = (gy >= 0 && gy < HH && gx >= 0 && gx < WW);
#pragma unroll
          for (int nt = 0; nt < 2; ++nt) {
            float v = okp ? fmaxf(a1[nt][r] + bias1[nt], 0.f) : 0.f;
            x1t[(ry * 18 + rx) * 36 + nt * 16 + lx] = f2bf(v);
          }
        }
      }
    }
  }
  __syncthreads();

  // ---- phase 3: conv2 MFMA (reads x1 from LDS) ----
  f32x4 acc[4][4];
#pragma unroll
  for (int mt = 0; mt < 4; ++mt)
#pragma unroll
    for (int nt = 0; nt < 4; ++nt) acc[mt][nt] = (f32x4)0.f;
#pragma unroll
  for (int kk = 0; kk < 9; ++kk) {
    int ky = kk / 3, kx = kk - ky * 3;
    short8 a[4], b[4];
#pragma unroll
    for (int mt = 0; mt < 4; ++mt) {
      int row = wid * 4 + mt;
      a[mt] = *(const short8*)&x1t[((row + ky) * 18 + lx + kx) * 36 + q * 8];
    }
#pragma unroll
    for (int nt = 0; nt < 4; ++nt) b[nt] = w2fv[(kk * 4 + nt) * 64 + lane];
#pragma unroll
    for (int mt = 0; mt < 4; ++mt)
#pragma unroll
      for (int nt = 0; nt < 4; ++nt)
        acc[mt][nt] = __builtin_amdgcn_mfma_f32_16x16x32_bf16(a[mt], b[nt], acc[mt][nt], 0, 0, 0);
  }
  __syncthreads();

  // ---- phase 4: relayout D -> [pixel][ch] bf16 (overlays buf[0..17408)) ----
#pragma unroll
  for (int nt = 0; nt < 4; ++nt) {
    float bias = b2f[nt * 16 + lx];
#pragma unroll
    for (int mt = 0; mt < 4; ++mt) {
      int row = wid * 4 + mt;
#pragma unroll
      for (int r = 0; r < 4; ++r) {
        int p = row * 16 + q * 4 + r;
        float v = fmaxf(acc[mt][nt][r] + bias, 0.f);
        buf[p * 68 + nt * 16 + lx] = f2bf(v);
      }
    }
  }
  __syncthreads();

  // ---- phase 5: conv3 1x1 64->8 via MFMA + store aff ----
  short8 bw3[2];
  bw3[0] = w3fv[lane];
  bw3[1] = w3fv[64 + lane];
  f32x4 acc3[4];
#pragma unroll
  for (int mt = 0; mt < 4; ++mt) acc3[mt] = (f32x4)0.f;
#pragma unroll
  for (int mt = 0; mt < 4; ++mt) {
    int p = wid * 64 + mt * 16 + lx;
#pragma unroll
    for (int s = 0; s < 2; ++s) {
      short8 a3 = *(const short8*)&buf[p * 68 + s * 32 + q * 8];
      acc3[mt] = __builtin_amdgcn_mfma_f32_16x16x32_bf16(a3, bw3[s], acc3[mt], 0, 0, 0);
    }
  }
  if (lx < 8) {
#pragma unroll
    for (int mt = 0; mt < 4; ++mt) {
      int py = ty0 + wid * 4 + mt;
      int px = tx0 + q * 4;
      u16x4 pk;
#pragma unroll
      for (int r = 0; r < 4; ++r) pk[r] = f2bf(fmaxf(acc3[mt][r], 0.f));
      *(u16x4*)&aff[((size_t)(n * 8 + lx)) * HW + (size_t)py * WW + px] = pk;
    }
  }
}

// ---------------- final: 8-neighbor softmax propagation, 4 px/thread ----------------
__global__ __launch_bounds__(256) void final_kernel(const float* __restrict__ disp,
                                                    const char* __restrict__ wsb,
                                                    float* __restrict__ out) {
  int gid = blockIdx.x * 256 + threadIdx.x;  // 131072 threads
  int n = gid >> 14;
  int r = gid & 16383;
  int i = r >> 6;
  int j0 = (r & 63) << 2;
  const ushort* aff = (const ushort*)(wsb + OFF_AFFB);
  float d6[3][6];
#pragma unroll
  for (int rr = 0; rr < 3; ++rr) {
    int y = min(max(i + rr - 1, 0), HH - 1);
    const float* dp = disp + (size_t)n * HW + y * WW;
    float4 c4 = *(const float4*)(dp + j0);
    d6[rr][1] = c4.x; d6[rr][2] = c4.y; d6[rr][3] = c4.z; d6[rr][4] = c4.w;
    d6[rr][0] = dp[max(j0 - 1, 0)];
    d6[rr][5] = dp[min(j0 + 4, WW - 1)];
  }
  const int dy[8] = {1, 1, 1, 0, 0, -1, -1, -1};
  const int dx[8] = {1, 0, -1, 1, -1, 1, 0, -1};
  float g[8][4], dvv[8][4];
#pragma unroll
  for (int k = 0; k < 8; ++k) {
    int y = i + dy[k];
    bool vy = (y >= 0 && y < HH);
    int yc = min(max(y, 0), HH - 1);
    const ushort* ap = aff + ((size_t)(n * 8 + k)) * HW + (size_t)yc * WW;
    float w6[6];
    u16x4 c4 = *(const u16x4*)(ap + j0);
    w6[1] = bf2f(c4[0]); w6[2] = bf2f(c4[1]); w6[3] = bf2f(c4[2]); w6[4] = bf2f(c4[3]);
    w6[0] = bf2f(ap[max(j0 - 1, 0)]);
    w6[5] = bf2f(ap[min(j0 + 4, WW - 1)]);
    int rr = dy[k] + 1;
#pragma unroll
    for (int p = 0; p < 4; ++p) {
      int xp = j0 + p + dx[k];
      bool ok = vy && (xp >= 0) && (xp < WW);
      g[k][p] = ok ? w6[p + 1 + dx[k]] : 0.f;
      dvv[k][p] = ok ? d6[rr][p + 1 + dx[k]] : 0.f;
    }
  }
  float4 res;
#pragma unroll
  for (int p = 0; p < 4; ++p) {
    float m = g[0][p];
#pragma unroll
    for (int k = 1; k < 8; ++k) m = fmaxf(m, g[k][p]);
    float se = 0.f, sed = 0.f;
#pragma unroll
    for (int k = 0; k < 8; ++k) {
      float e = __expf(g[k][p] - m);
      se += e;
      sed += e * dvv[k][p];
    }
    float dc = d6[1][p + 1];
    (&res.x)[p] = 0.3f * (sed / se) + 0.7f * dc;
  }
  *(float4*)(out + (size_t)n * HW + i * WW + j0) = res;
}

extern "C" void kernel_launch(void* const* d_in, const int* in_sizes, int n_in,
                              void* d_out, int out_size, void* d_ws, size_t ws_size,
                              hipStream_t stream) {
  const float* normal = (const float*)d_in[0];
  const float* left   = (const float*)d_in[1];
  const float* right  = (const float*)d_in[2];
  const float* disp   = (const float*)d_in[3];
  const float* w1 = (const float*)d_in[4];
  const float* g1 = (const float*)d_in[5];
  const float* b1 = (const float*)d_in[6];
  const float* m1 = (const float*)d_in[7];
  const float* v1 = (const float*)d_in[8];
  const float* w2 = (const float*)d_in[9];
  const float* g2 = (const float*)d_in[10];
  const float* b2 = (const float*)d_in[11];
  const float* m2 = (const float*)d_in[12];
  const float* v2 = (const float*)d_in[13];
  const float* w3 = (const float*)d_in[14];
  char* wsb  = (char*)d_ws;
  float* out = (float*)d_out;

  hipLaunchKernelGGL(prep_weights, dim3(101), dim3(256), 0, stream,
                     w1, g1, b1, m1, v1, w2, g2, b2, m2, v2, w3, wsb);
  hipLaunchKernelGGL(trunk_kernel, dim3(2048), dim3(256), 0, stream,
                     normal, left, right, disp, wsb);
  hipLaunchKernelGGL(final_kernel, dim3(512), dim3(256), 0, stream, disp, wsb, out);
}

// Round 8
// 168.365 us; speedup vs baseline: 1.0037x; 1.0037x over previous
//
#include <hip/hip_runtime.h>
#include <math.h>

#define NB 8
#define HH 256
#define WW 256
#define HW (HH*WW)

// ---- workspace layout (BYTE offsets) ----
#define OFF_AFFB  0UL                 // [8][8][256][256] bf16 (8388608 B)
#define OFF_W1FB  8388608UL           // [6][2][64][8] bf16 frag order (12288 B)
#define OFF_B1FB  8400896UL           // [32] fp32
#define OFF_W2FB  8401024UL           // [9][4][64][8] bf16 B-frag order (36864 B)
#define OFF_B2FB  8437888UL           // [64] fp32
#define OFF_W3FB  8438144UL           // [2][64][8] bf16 B-frag order (2048 B)
#define OFF_PACK  8440192UL           // [8][256][256][12] fp32 (25165824 B)
// pack record: {cl0,cl1,cl2, cr0,cr1,cr2, nm0,nm1,nm2, disp, 0,0}

typedef short  short8 __attribute__((ext_vector_type(8)));
typedef ushort u16x8  __attribute__((ext_vector_type(8)));
typedef ushort u16x4  __attribute__((ext_vector_type(4)));
typedef float  f32x4  __attribute__((ext_vector_type(4)));

__device__ __forceinline__ ushort f2bf(float x) {
  uint u = __float_as_uint(x);
  return (ushort)((u + 0x7FFFu + ((u >> 16) & 1u)) >> 16);
}
__device__ __forceinline__ float bf2f(ushort h) {
  uint u = ((uint)h) << 16;
  return __uint_as_float(u);
}

// ---------------- resize+pack (blocks<1024, 2px/thread) + weight prep (blocks>=1024) ----------------
__global__ __launch_bounds__(256) void resize_pack(
    const float* __restrict__ normal, const float* __restrict__ left,
    const float* __restrict__ right, const float* __restrict__ disp,
    const float* __restrict__ w1, const float* __restrict__ g1,
    const float* __restrict__ b1, const float* __restrict__ m1,
    const float* __restrict__ v1,
    const float* __restrict__ w2, const float* __restrict__ g2,
    const float* __restrict__ b2, const float* __restrict__ m2,
    const float* __restrict__ v2, const float* __restrict__ w3,
    char* __restrict__ wsb) {
  if (blockIdx.x >= 1024) {
    int idx = (blockIdx.x - 1024) * 256 + threadIdx.x;
    ushort* w1f = (ushort*)(wsb + OFF_W1FB);
    float* b1f  = (float*)(wsb + OFF_B1FB);
    ushort* w2f = (ushort*)(wsb + OFF_W2FB);
    float* b2f  = (float*)(wsb + OFF_B2FB);
    ushort* w3f = (ushort*)(wsb + OFF_W3FB);
    if (idx < 6144) {
      int jj = idx & 7;
      int lane = (idx >> 3) & 63;
      int nt = (idx >> 9) & 1;
      int s = idx >> 10;
      int ky = s >> 1, t = s & 1;
      int q = lane >> 4, lx = lane & 15;
      int k = q * 8 + jj;
      int dcol = k >> 4, ch = k & 15;
      int kx = t * 2 + dcol;
      int out = nt * 16 + lx;
      float inv = g1[out] / sqrtf(v1[out] + 1e-5f);
      float val = (ch < 12 && kx < 3) ? w1[((out * 12 + ch) * 3 + ky) * 3 + kx] * inv : 0.f;
      w1f[idx] = f2bf(val);
    }
    int j = idx - 6144;
    if (j >= 0 && j < 18432) {
      int kk   = j >> 11;
      int nt   = (j >> 9) & 3;
      int lane = (j >> 3) & 63;
      int jj   = j & 7;
      int q  = lane >> 4, lx = lane & 15;
      int cin = q * 8 + jj;
      int out = nt * 16 + lx;
      float inv = g2[out] / sqrtf(v2[out] + 1e-5f);
      w2f[j] = f2bf(w2[(out * 32 + cin) * 9 + kk] * inv);
      if (kk == 0 && q == 0 && jj == 0) b2f[out] = b2[out] - m2[out] * inv;
    }
    int k2 = idx - 24576;
    if (k2 >= 0 && k2 < 32) {
      float inv = g1[k2] / sqrtf(v1[k2] + 1e-5f);
      b1f[k2] = b1[k2] - m1[k2] * inv;
    }
    int k3 = idx - 24608;
    if (k3 >= 0 && k3 < 1024) {
      int jj = k3 & 7;
      int lane = (k3 >> 3) & 63;
      int slice = k3 >> 9;
      int q = lane >> 4, lx = lane & 15;
      int ch = slice * 32 + q * 8 + jj;
      w3f[k3] = (lx < 8) ? f2bf(w3[lx * 64 + ch]) : (ushort)0;
    }
    return;
  }
  int gid = blockIdx.x * 256 + threadIdx.x;   // 262144 threads, 2 px each
  int n = gid >> 15;
  int r = gid & 32767;
  int i = r >> 7;
  int j0 = (r & 127) << 1;
  int i2 = i << 1;
  float* pack = (float*)(wsb + OFF_PACK);
  float rec[2][12];
#pragma unroll
  for (int c = 0; c < 3; ++c) {
    const float* Lp = left + ((size_t)(n * 3 + c) * 512 + i2) * 512 + (j0 << 1);
    float4 a0 = *(const float4*)Lp;
    float4 a1 = *(const float4*)(Lp + 512);
    rec[0][c] = 0.25f * (a0.x + a0.y + a1.x + a1.y);
    rec[1][c] = 0.25f * (a0.z + a0.w + a1.z + a1.w);
    const float* Rp = right + ((size_t)(n * 3 + c) * 512 + i2) * 512 + (j0 << 1);
    float4 b0 = *(const float4*)Rp;
    float4 b1v = *(const float4*)(Rp + 512);
    rec[0][3 + c] = 0.25f * (b0.x + b0.y + b1v.x + b1v.y);
    rec[1][3 + c] = 0.25f * (b0.z + b0.w + b1v.z + b1v.w);
    float2 nm = *(const float2*)(normal + (size_t)(n * 3 + c) * HW + i * 256 + j0);
    rec[0][6 + c] = nm.x;
    rec[1][6 + c] = nm.y;
  }
  float2 dp2 = *(const float2*)(disp + (size_t)n * HW + i * 256 + j0);
  rec[0][9] = dp2.x; rec[1][9] = dp2.y;
  rec[0][10] = 0.f; rec[0][11] = 0.f; rec[1][10] = 0.f; rec[1][11] = 0.f;
  float* ob = pack + ((size_t)(n * HW + i * 256 + j0)) * 12;
#pragma unroll
  for (int p = 0; p < 2; ++p)
#pragma unroll
    for (int vv = 0; vv < 3; ++vv)
      *(float4*)(ob + p * 12 + vv * 4) = *(float4*)&rec[p][vv * 4];
}

// ---------------- trunk: feats (from pack) + conv1 + conv2 + conv3 ----------------
// LDS: buf[0..6464) = 808 16B chunks: feats tile [20][20][16ch], XOR-swizzled
//      buf[6464..18128) = x1 tile [18*18][36]; relayout overlays buf[0..17408)
__global__ __launch_bounds__(256) void trunk_kernel(char* __restrict__ wsb) {
  __shared__ ushort buf[18304];  // 36608 B
  ushort* x1t = buf + 6464;
  const short8* __restrict__ w1fv = (const short8*)(wsb + OFF_W1FB);
  const float* __restrict__ b1f = (const float*)(wsb + OFF_B1FB);
  const short8* __restrict__ w2fv = (const short8*)(wsb + OFF_W2FB);
  const float* __restrict__ b2f = (const float*)(wsb + OFF_B2FB);
  const short8* __restrict__ w3fv = (const short8*)(wsb + OFF_W3FB);
  const float* __restrict__ pack = (const float*)(wsb + OFF_PACK);
  ushort* aff = (ushort*)(wsb + OFF_AFFB);

  int blk = blockIdx.x;
  int n = blk >> 8;
  int t = blk & 255;
  int ty0 = (t >> 4) << 4;
  int tx0 = (t & 15) << 4;
  int tid = threadIdx.x;
  int lane = tid & 63;
  int wid = tid >> 6;
  int q = lane >> 4;
  int lx = lane & 15;

  // ---- phase 1: feats for 20x20 halo -> LDS (swizzled chunks) ----
  if (tid < 8) *(u16x8*)&buf[(800 + tid) * 8] = (u16x8)0;
  for (int e = tid; e < 400; e += 256) {
    int row = e / 20, col = e - row * 20;
    int gy = ty0 + row - 2, gx = tx0 + col - 2;
    ushort tmp[16];
#pragma unroll
    for (int c = 12; c < 16; ++c) tmp[c] = 0;
    if (gy >= 0 && gy < HH && gx >= 0 && gx < WW) {
      const float* P = pack + ((size_t)((n << 16) + gy * 256 + gx)) * 12;
      float4 r0 = *(const float4*)P;        // cl0 cl1 cl2 cr0
      float4 r1 = *(const float4*)(P + 4);  // cr1 cr2 nm0 nm1
      float4 r2 = *(const float4*)(P + 8);  // nm2 d 0 0
      float cl[3] = {r0.x, r0.y, r0.z};
      float cr[3] = {r0.w, r1.x, r1.y};
      tmp[0] = f2bf(r1.z); tmp[1] = f2bf(r1.w); tmp[2] = f2bf(r2.x);
      tmp[3] = f2bf(cl[0]); tmp[4] = f2bf(cl[1]); tmp[5] = f2bf(cl[2]);
      tmp[6] = f2bf(cr[0]); tmp[7] = f2bf(cr[1]); tmp[8] = f2bf(cr[2]);
      float d = r2.y;
      float xs = (float)gx - d;
      float x0f = floorf(xs);
      float fr = xs - x0f;
      int ix0 = (int)x0f;
      int ix1 = ix0 + 1;
      float vm0 = (ix0 >= 0 && ix0 < WW) ? 1.f : 0.f;
      float vm1 = (ix1 >= 0 && ix1 < WW) ? 1.f : 0.f;
      int x0c = min(max(ix0, 0), WW - 1);
      int x1c = min(max(ix1, 0), WW - 1);
      const float* R0 = pack + ((size_t)((n << 16) + gy * 256 + x0c)) * 12 + 3;
      const float* R1 = pack + ((size_t)((n << 16) + gy * 256 + x1c)) * 12 + 3;
#pragma unroll
      for (int c = 0; c < 3; ++c) {
        float warped = R0[c] * vm0 * (1.f - fr) + R1[c] * vm1 * fr;
        tmp[9 + c] = f2bf(fabsf(cl[c] - warped));
      }
    } else {
#pragma unroll
      for (int c = 0; c < 12; ++c) tmp[c] = 0;
    }
    int G0 = e * 2, G1 = G0 + 1;
    int s0 = G0 ^ ((G0 >> 3) & 7);
    int s1 = G1 ^ ((G1 >> 3) & 7);
    *(u16x8*)&buf[s0 * 8] = *(u16x8*)&tmp[0];
    *(u16x8*)&buf[s1 * 8] = *(u16x8*)&tmp[8];
  }
  __syncthreads();

  // ---- phase 2: conv1 MFMA over 18x18 halo outputs; A=pixels, B=weights ----
  {
    short8 bw1[6][2];
#pragma unroll
    for (int s = 0; s < 6; ++s)
#pragma unroll
      for (int nt = 0; nt < 2; ++nt) bw1[s][nt] = w1fv[(s * 2 + nt) * 64 + lane];
    float bias1[2] = {b1f[lx], b1f[16 + lx]};
    for (int m = wid; m < 21; m += 4) {
      int pidx = min(m * 16 + lx, 323);
      int oyr = pidx / 18, oxr = pidx - oyr * 18;
      f32x4 a1[2];
      a1[0] = (f32x4)0.f; a1[1] = (f32x4)0.f;
#pragma unroll
      for (int s = 0; s < 6; ++s) {
        int ky = s >> 1, tt = s & 1;
        int G = ((oyr + ky) * 20 + oxr + tt * 2 + (q >> 1)) * 2 + (q & 1);
        int slot = G ^ ((G >> 3) & 7);
        short8 a = *(const short8*)&buf[slot * 8];
        a1[0] = __builtin_amdgcn_mfma_f32_16x16x32_bf16(a, bw1[s][0], a1[0], 0, 0, 0);
        a1[1] = __builtin_amdgcn_mfma_f32_16x16x32_bf16(a, bw1[s][1], a1[1], 0, 0, 0);
      }
#pragma unroll
      for (int r = 0; r < 4; ++r) {
        int p2 = m * 16 + q * 4 + r;
        if (p2 < 324) {
          int ry = p2 / 18, rx = p2 - ry * 18;
          int gy = ty0 + ry - 1, gx = tx0 + rx - 1;
          bool okp = (gy >= 0 && gy < HH && gx >= 0 && gx < WW);
#pragma unroll
          for (int nt = 0; nt < 2; ++nt) {
            float v = okp ? fmaxf(a1[nt][r] + bias1[nt], 0.f) : 0.f;
            x1t[(ry * 18 + rx) * 36 + nt * 16 + lx] = f2bf(v);
          }
        }
      }
    }
  }
  __syncthreads();

  // ---- phase 3: conv2 MFMA (x1 from LDS) ----
  f32x4 acc[4][4];
#pragma unroll
  for (int mt = 0; mt < 4; ++mt)
#pragma unroll
    for (int nt = 0; nt < 4; ++nt) acc[mt][nt] = (f32x4)0.f;
#pragma unroll
  for (int kk = 0; kk < 9; ++kk) {
    int ky = kk / 3, kx = kk - ky * 3;
    short8 a[4], b[4];
#pragma unroll
    for (int mt = 0; mt < 4; ++mt) {
      int row = wid * 4 + mt;
      a[mt] = *(const short8*)&x1t[((row + ky) * 18 + lx + kx) * 36 + q * 8];
    }
#pragma unroll
    for (int nt = 0; nt < 4; ++nt) b[nt] = w2fv[(kk * 4 + nt) * 64 + lane];
#pragma unroll
    for (int mt = 0; mt < 4; ++mt)
#pragma unroll
      for (int nt = 0; nt < 4; ++nt)
        acc[mt][nt] = __builtin_amdgcn_mfma_f32_16x16x32_bf16(a[mt], b[nt], acc[mt][nt], 0, 0, 0);
  }
  __syncthreads();

  // ---- phase 4: relayout D -> [pixel][ch] bf16 ----
#pragma unroll
  for (int nt = 0; nt < 4; ++nt) {
    float bias = b2f[nt * 16 + lx];
#pragma unroll
    for (int mt = 0; mt < 4; ++mt) {
      int row = wid * 4 + mt;
#pragma unroll
      for (int r = 0; r < 4; ++r) {
        int p = row * 16 + q * 4 + r;
        float v = fmaxf(acc[mt][nt][r] + bias, 0.f);
        buf[p * 68 + nt * 16 + lx] = f2bf(v);
      }
    }
  }
  __syncthreads();

  // ---- phase 5: conv3 1x1 64->8 via MFMA + store aff ----
  short8 bw3[2];
  bw3[0] = w3fv[lane];
  bw3[1] = w3fv[64 + lane];
  f32x4 acc3[4];
#pragma unroll
  for (int mt = 0; mt < 4; ++mt) acc3[mt] = (f32x4)0.f;
#pragma unroll
  for (int mt = 0; mt < 4; ++mt) {
    int p = wid * 64 + mt * 16 + lx;
#pragma unroll
    for (int s = 0; s < 2; ++s) {
      short8 a3 = *(const short8*)&buf[p * 68 + s * 32 + q * 8];
      acc3[mt] = __builtin_amdgcn_mfma_f32_16x16x32_bf16(a3, bw3[s], acc3[mt], 0, 0, 0);
    }
  }
  if (lx < 8) {
#pragma unroll
    for (int mt = 0; mt < 4; ++mt) {
      int py = ty0 + wid * 4 + mt;
      int px = tx0 + q * 4;
      u16x4 pk;
#pragma unroll
      for (int r = 0; r < 4; ++r) pk[r] = f2bf(fmaxf(acc3[mt][r], 0.f));
      *(u16x4*)&aff[((size_t)(n * 8 + lx)) * HW + (size_t)py * WW + px] = pk;
    }
  }
}

// ---------------- final: 8-neighbor softmax propagation, 4 px/thread ----------------
__global__ __launch_bounds__(256) void final_kernel(const float* __restrict__ disp,
                                                    const char* __restrict__ wsb,
                                                    float* __restrict__ out) {
  int gid = blockIdx.x * 256 + threadIdx.x;
  int n = gid >> 14;
  int r = gid & 16383;
  int i = r >> 6;
  int j0 = (r & 63) << 2;
  const ushort* aff = (const ushort*)(wsb + OFF_AFFB);
  float d6[3][6];
#pragma unroll
  for (int rr = 0; rr < 3; ++rr) {
    int y = min(max(i + rr - 1, 0), HH - 1);
    const float* dp = disp + (size_t)n * HW + y * WW;
    float4 c4 = *(const float4*)(dp + j0);
    d6[rr][1] = c4.x; d6[rr][2] = c4.y; d6[rr][3] = c4.z; d6[rr][4] = c4.w;
    d6[rr][0] = dp[max(j0 - 1, 0)];
    d6[rr][5] = dp[min(j0 + 4, WW - 1)];
  }
  const int dy[8] = {1, 1, 1, 0, 0, -1, -1, -1};
  const int dx[8] = {1, 0, -1, 1, -1, 1, 0, -1};
  float g[8][4], dvv[8][4];
#pragma unroll
  for (int k = 0; k < 8; ++k) {
    int y = i + dy[k];
    bool vy = (y >= 0 && y < HH);
    int yc = min(max(y, 0), HH - 1);
    const ushort* ap = aff + ((size_t)(n * 8 + k)) * HW + (size_t)yc * WW;
    float w6[6];
    u16x4 c4 = *(const u16x4*)(ap + j0);
    w6[1] = bf2f(c4[0]); w6[2] = bf2f(c4[1]); w6[3] = bf2f(c4[2]); w6[4] = bf2f(c4[3]);
    w6[0] = bf2f(ap[max(j0 - 1, 0)]);
    w6[5] = bf2f(ap[min(j0 + 4, WW - 1)]);
    int rr = dy[k] + 1;
#pragma unroll
    for (int p = 0; p < 4; ++p) {
      int xp = j0 + p + dx[k];
      bool ok = vy && (xp >= 0) && (xp < WW);
      g[k][p] = ok ? w6[p + 1 + dx[k]] : 0.f;
      dvv[k][p] = ok ? d6[rr][p + 1 + dx[k]] : 0.f;
    }
  }
  float4 res;
#pragma unroll
  for (int p = 0; p < 4; ++p) {
    float m = g[0][p];
#pragma unroll
    for (int k = 1; k < 8; ++k) m = fmaxf(m, g[k][p]);
    float se = 0.f, sed = 0.f;
#pragma unroll
    for (int k = 0; k < 8; ++k) {
      float e = __expf(g[k][p] - m);
      se += e;
      sed += e * dvv[k][p];
    }
    float dc = d6[1][p + 1];
    (&res.x)[p] = 0.3f * (sed / se) + 0.7f * dc;
  }
  *(float4*)(out + (size_t)n * HW + i * WW + j0) = res;
}

extern "C" void kernel_launch(void* const* d_in, const int* in_sizes, int n_in,
                              void* d_out, int out_size, void* d_ws, size_t ws_size,
                              hipStream_t stream) {
  const float* normal = (const float*)d_in[0];
  const float* left   = (const float*)d_in[1];
  const float* right  = (const float*)d_in[2];
  const float* disp   = (const float*)d_in[3];
  const float* w1 = (const float*)d_in[4];
  const float* g1 = (const float*)d_in[5];
  const float* b1 = (const float*)d_in[6];
  const float* m1 = (const float*)d_in[7];
  const float* v1 = (const float*)d_in[8];
  const float* w2 = (const float*)d_in[9];
  const float* g2 = (const float*)d_in[10];
  const float* b2 = (const float*)d_in[11];
  const float* m2 = (const float*)d_in[12];
  const float* v2 = (const float*)d_in[13];
  const float* w3 = (const float*)d_in[14];
  char* wsb  = (char*)d_ws;
  float* out = (float*)d_out;

  hipLaunchKernelGGL(resize_pack, dim3(1125), dim3(256), 0, stream,
                     normal, left, right, disp,
                     w1, g1, b1, m1, v1, w2, g2, b2, m2, v2, w3, wsb);
  hipLaunchKernelGGL(trunk_kernel, dim3(2048), dim3(256), 0, stream, wsb);
  hipLaunchKernelGGL(final_kernel, dim3(512), dim3(256), 0, stream, disp, wsb, out);
}

// Round 9
// 161.521 us; speedup vs baseline: 1.0463x; 1.0424x over previous
//
#include <hip/hip_runtime.h>
#include <math.h>

#define NB 8
#define HH 256
#define WW 256
#define HW (HH*WW)

// ---- workspace layout (BYTE offsets) ----
#define OFF_AFFB  0UL                 // [8][8][256][256] bf16 (8388608 B)
#define OFF_W1FB  8388608UL           // [6][2][64][8] bf16 frag order (12288 B)
#define OFF_B1FB  8400896UL           // [32] fp32
#define OFF_W2FB  8401024UL           // [9][4][64][8] bf16 B-frag order (36864 B)
#define OFF_B2FB  8437888UL           // [64] fp32
#define OFF_W3FB  8438144UL           // [2][64][8] bf16 B-frag order (2048 B)
#define OFF_FEATS 8440192UL           // [8][256][256][16] bf16 (16777216 B)

typedef short  short8 __attribute__((ext_vector_type(8)));
typedef ushort u16x8  __attribute__((ext_vector_type(8)));
typedef ushort u16x4  __attribute__((ext_vector_type(4)));
typedef float  f32x4  __attribute__((ext_vector_type(4)));

__device__ __forceinline__ ushort f2bf(float x) {
  uint u = __float_as_uint(x);
  return (ushort)((u + 0x7FFFu + ((u >> 16) & 1u)) >> 16);
}
__device__ __forceinline__ float bf2f(ushort h) {
  uint u = ((uint)h) << 16;
  return __uint_as_float(u);
}

// ---------------- feats_row (blocks<2048): full feats, 1 row/block, gather via LDS ----------------
// blocks>=2048: weight prep
__global__ __launch_bounds__(256) void feats_row(
    const float* __restrict__ normal, const float* __restrict__ left,
    const float* __restrict__ right, const float* __restrict__ disp,
    const float* __restrict__ w1, const float* __restrict__ g1,
    const float* __restrict__ b1, const float* __restrict__ m1,
    const float* __restrict__ v1,
    const float* __restrict__ w2, const float* __restrict__ g2,
    const float* __restrict__ b2, const float* __restrict__ m2,
    const float* __restrict__ v2, const float* __restrict__ w3,
    char* __restrict__ wsb) {
  if (blockIdx.x >= 2048) {
    int idx = (blockIdx.x - 2048) * 256 + threadIdx.x;
    ushort* w1f = (ushort*)(wsb + OFF_W1FB);
    float* b1f  = (float*)(wsb + OFF_B1FB);
    ushort* w2f = (ushort*)(wsb + OFF_W2FB);
    float* b2f  = (float*)(wsb + OFF_B2FB);
    ushort* w3f = (ushort*)(wsb + OFF_W3FB);
    if (idx < 6144) {
      int jj = idx & 7;
      int lane = (idx >> 3) & 63;
      int nt = (idx >> 9) & 1;
      int s = idx >> 10;
      int ky = s >> 1, t = s & 1;
      int q = lane >> 4, lx = lane & 15;
      int k = q * 8 + jj;
      int dcol = k >> 4, ch = k & 15;
      int kx = t * 2 + dcol;
      int out = nt * 16 + lx;
      float inv = g1[out] / sqrtf(v1[out] + 1e-5f);
      float val = (ch < 12 && kx < 3) ? w1[((out * 12 + ch) * 3 + ky) * 3 + kx] * inv : 0.f;
      w1f[idx] = f2bf(val);
    }
    int j = idx - 6144;
    if (j >= 0 && j < 18432) {
      int kk   = j >> 11;
      int nt   = (j >> 9) & 3;
      int lane = (j >> 3) & 63;
      int jj   = j & 7;
      int q  = lane >> 4, lx = lane & 15;
      int cin = q * 8 + jj;
      int out = nt * 16 + lx;
      float inv = g2[out] / sqrtf(v2[out] + 1e-5f);
      w2f[j] = f2bf(w2[(out * 32 + cin) * 9 + kk] * inv);
      if (kk == 0 && q == 0 && jj == 0) b2f[out] = b2[out] - m2[out] * inv;
    }
    int k2 = idx - 24576;
    if (k2 >= 0 && k2 < 32) {
      float inv = g1[k2] / sqrtf(v1[k2] + 1e-5f);
      b1f[k2] = b1[k2] - m1[k2] * inv;
    }
    int k3 = idx - 24608;
    if (k3 >= 0 && k3 < 1024) {
      int jj = k3 & 7;
      int lane = (k3 >> 3) & 63;
      int slice = k3 >> 9;
      int q = lane >> 4, lx = lane & 15;
      int ch = slice * 32 + q * 8 + jj;
      w3f[k3] = (lx < 8) ? f2bf(w3[lx * 64 + ch]) : (ushort)0;
    }
    return;
  }
  // one block = one output row (n, i); one thread = one pixel j
  __shared__ float curR[3][256];
  int blk = blockIdx.x;
  int n = blk >> 8;
  int i = blk & 255;
  int j = threadIdx.x;
  int i2 = i << 1;
  ushort* feats = (ushort*)(wsb + OFF_FEATS);
  float cl[3], cr[3];
#pragma unroll
  for (int c = 0; c < 3; ++c) {
    const float* Lp = left + ((size_t)(n * 3 + c) * 512 + i2) * 512 + (j << 1);
    float2 a0 = *(const float2*)Lp;
    float2 a1 = *(const float2*)(Lp + 512);
    cl[c] = 0.25f * (a0.x + a0.y + a1.x + a1.y);
    const float* Rp = right + ((size_t)(n * 3 + c) * 512 + i2) * 512 + (j << 1);
    float2 b0 = *(const float2*)Rp;
    float2 b1v = *(const float2*)(Rp + 512);
    cr[c] = 0.25f * (b0.x + b0.y + b1v.x + b1v.y);
    curR[c][j] = cr[c];
  }
  float nm[3];
#pragma unroll
  for (int c = 0; c < 3; ++c)
    nm[c] = normal[(size_t)(n * 3 + c) * HW + i * WW + j];
  float d = disp[(size_t)n * HW + i * WW + j];
  __syncthreads();
  float xs = (float)j - d;
  float x0f = floorf(xs);
  float fr = xs - x0f;
  int ix0 = (int)x0f;
  int ix1 = ix0 + 1;
  float vm0 = (ix0 >= 0 && ix0 < WW) ? 1.f : 0.f;
  float vm1 = (ix1 >= 0 && ix1 < WW) ? 1.f : 0.f;
  int x0c = min(max(ix0, 0), WW - 1);
  int x1c = min(max(ix1, 0), WW - 1);
  ushort tmp[16];
#pragma unroll
  for (int c = 0; c < 3; ++c) {
    float warped = curR[c][x0c] * vm0 * (1.f - fr) + curR[c][x1c] * vm1 * fr;
    tmp[9 + c] = f2bf(fabsf(cl[c] - warped));
    tmp[c] = f2bf(nm[c]);
    tmp[3 + c] = f2bf(cl[c]);
    tmp[6 + c] = f2bf(cr[c]);
  }
#pragma unroll
  for (int c = 12; c < 16; ++c) tmp[c] = 0;
  size_t ob = ((size_t)((n << 16) + i * WW + j)) * 16;
  *(u16x8*)&feats[ob] = *(u16x8*)&tmp[0];
  *(u16x8*)&feats[ob + 8] = *(u16x8*)&tmp[8];
}

// ---------------- trunk: stage feats tile + conv1 + conv2 + conv3 ----------------
// LDS: buf[0..6464) = 808 16B chunks: feats tile [20][20][16ch], XOR-swizzled
//      buf[6464..18128) = x1 tile [18*18][36]; relayout overlays buf[0..17408)
__global__ __launch_bounds__(256) void trunk_kernel(char* __restrict__ wsb) {
  __shared__ ushort buf[18304];  // 36608 B
  ushort* x1t = buf + 6464;
  const short8* __restrict__ w1fv = (const short8*)(wsb + OFF_W1FB);
  const float* __restrict__ b1f = (const float*)(wsb + OFF_B1FB);
  const short8* __restrict__ w2fv = (const short8*)(wsb + OFF_W2FB);
  const float* __restrict__ b2f = (const float*)(wsb + OFF_B2FB);
  const short8* __restrict__ w3fv = (const short8*)(wsb + OFF_W3FB);
  const ushort* __restrict__ feats = (const ushort*)(wsb + OFF_FEATS);
  ushort* aff = (ushort*)(wsb + OFF_AFFB);

  int blk = blockIdx.x;
  int n = blk >> 8;
  int t = blk & 255;
  int ty0 = (t >> 4) << 4;
  int tx0 = (t & 15) << 4;
  int tid = threadIdx.x;
  int lane = tid & 63;
  int wid = tid >> 6;
  int q = lane >> 4;
  int lx = lane & 15;

  // ---- phase 1: stage feats 20x20x16 bf16 tile (XOR-swizzled 16B chunks) ----
  if (tid < 8) *(u16x8*)&buf[(800 + tid) * 8] = (u16x8)0;
  for (int e = tid; e < 800; e += 256) {
    int row = e / 40;
    int rem = e - row * 40;
    int col = rem >> 1;
    int cc = rem & 1;
    int gy = ty0 + row - 2, gx = tx0 + col - 2;
    u16x8 v = (u16x8)0;
    if (gy >= 0 && gy < HH && gx >= 0 && gx < WW)
      v = *(const u16x8*)&feats[((size_t)((n << 16) + gy * WW + gx)) * 16 + cc * 8];
    int slot = e ^ ((e >> 3) & 7);
    *(u16x8*)&buf[slot * 8] = v;
  }
  __syncthreads();

  // ---- phase 2: conv1 MFMA over 18x18 halo outputs; A=pixels, B=weights ----
  {
    short8 bw1[6][2];
#pragma unroll
    for (int s = 0; s < 6; ++s)
#pragma unroll
      for (int nt = 0; nt < 2; ++nt) bw1[s][nt] = w1fv[(s * 2 + nt) * 64 + lane];
    float bias1[2] = {b1f[lx], b1f[16 + lx]};
    for (int m = wid; m < 21; m += 4) {
      int pidx = min(m * 16 + lx, 323);
      int oyr = pidx / 18, oxr = pidx - oyr * 18;
      f32x4 a1[2];
      a1[0] = (f32x4)0.f; a1[1] = (f32x4)0.f;
#pragma unroll
      for (int s = 0; s < 6; ++s) {
        int ky = s >> 1, tt = s & 1;
        int G = ((oyr + ky) * 20 + oxr + tt * 2 + (q >> 1)) * 2 + (q & 1);
        int slot = G ^ ((G >> 3) & 7);
        short8 a = *(const short8*)&buf[slot * 8];
        a1[0] = __builtin_amdgcn_mfma_f32_16x16x32_bf16(a, bw1[s][0], a1[0], 0, 0, 0);
        a1[1] = __builtin_amdgcn_mfma_f32_16x16x32_bf16(a, bw1[s][1], a1[1], 0, 0, 0);
      }
#pragma unroll
      for (int r = 0; r < 4; ++r) {
        int p2 = m * 16 + q * 4 + r;
        if (p2 < 324) {
          int ry = p2 / 18, rx = p2 - ry * 18;
          int gy = ty0 + ry - 1, gx = tx0 + rx - 1;
          bool okp = (gy >= 0 && gy < HH && gx >= 0 && gx < WW);
#pragma unroll
          for (int nt = 0; nt < 2; ++nt) {
            float v = okp ? fmaxf(a1[nt][r] + bias1[nt], 0.f) : 0.f;
            x1t[(ry * 18 + rx) * 36 + nt * 16 + lx] = f2bf(v);
          }
        }
      }
    }
  }
  __syncthreads();

  // ---- phase 3: conv2 MFMA (x1 from LDS) ----
  f32x4 acc[4][4];
#pragma unroll
  for (int mt = 0; mt < 4; ++mt)
#pragma unroll
    for (int nt = 0; nt < 4; ++nt) acc[mt][nt] = (f32x4)0.f;
#pragma unroll
  for (int kk = 0; kk < 9; ++kk) {
    int ky = kk / 3, kx = kk - ky * 3;
    short8 a[4], b[4];
#pragma unroll
    for (int mt = 0; mt < 4; ++mt) {
      int row = wid * 4 + mt;
      a[mt] = *(const short8*)&x1t[((row + ky) * 18 + lx + kx) * 36 + q * 8];
    }
#pragma unroll
    for (int nt = 0; nt < 4; ++nt) b[nt] = w2fv[(kk * 4 + nt) * 64 + lane];
#pragma unroll
    for (int mt = 0; mt < 4; ++mt)
#pragma unroll
      for (int nt = 0; nt < 4; ++nt)
        acc[mt][nt] = __builtin_amdgcn_mfma_f32_16x16x32_bf16(a[mt], b[nt], acc[mt][nt], 0, 0, 0);
  }
  __syncthreads();

  // ---- phase 4: relayout D -> [pixel][ch] bf16 ----
#pragma unroll
  for (int nt = 0; nt < 4; ++nt) {
    float bias = b2f[nt * 16 + lx];
#pragma unroll
    for (int mt = 0; mt < 4; ++mt) {
      int row = wid * 4 + mt;
#pragma unroll
      for (int r = 0; r < 4; ++r) {
        int p = row * 16 + q * 4 + r;
        float v = fmaxf(acc[mt][nt][r] + bias, 0.f);
        buf[p * 68 + nt * 16 + lx] = f2bf(v);
      }
    }
  }
  __syncthreads();

  // ---- phase 5: conv3 1x1 64->8 via MFMA + store aff ----
  short8 bw3[2];
  bw3[0] = w3fv[lane];
  bw3[1] = w3fv[64 + lane];
  f32x4 acc3[4];
#pragma unroll
  for (int mt = 0; mt < 4; ++mt) acc3[mt] = (f32x4)0.f;
#pragma unroll
  for (int mt = 0; mt < 4; ++mt) {
    int p = wid * 64 + mt * 16 + lx;
#pragma unroll
    for (int s = 0; s < 2; ++s) {
      short8 a3 = *(const short8*)&buf[p * 68 + s * 32 + q * 8];
      acc3[mt] = __builtin_amdgcn_mfma_f32_16x16x32_bf16(a3, bw3[s], acc3[mt], 0, 0, 0);
    }
  }
  if (lx < 8) {
#pragma unroll
    for (int mt = 0; mt < 4; ++mt) {
      int py = ty0 + wid * 4 + mt;
      int px = tx0 + q * 4;
      u16x4 pk;
#pragma unroll
      for (int r = 0; r < 4; ++r) pk[r] = f2bf(fmaxf(acc3[mt][r], 0.f));
      *(u16x4*)&aff[((size_t)(n * 8 + lx)) * HW + (size_t)py * WW + px] = pk;
    }
  }
}

// ---------------- final: 8-neighbor softmax propagation, 4 px/thread ----------------
__global__ __launch_bounds__(256) void final_kernel(const float* __restrict__ disp,
                                                    const char* __restrict__ wsb,
                                                    float* __restrict__ out) {
  int gid = blockIdx.x * 256 + threadIdx.x;
  int n = gid >> 14;
  int r = gid & 16383;
  int i = r >> 6;
  int j0 = (r & 63) << 2;
  const ushort* aff = (const ushort*)(wsb + OFF_AFFB);
  float d6[3][6];
#pragma unroll
  for (int rr = 0; rr < 3; ++rr) {
    int y = min(max(i + rr - 1, 0), HH - 1);
    const float* dp = disp + (size_t)n * HW + y * WW;
    float4 c4 = *(const float4*)(dp + j0);
    d6[rr][1] = c4.x; d6[rr][2] = c4.y; d6[rr][3] = c4.z; d6[rr][4] = c4.w;
    d6[rr][0] = dp[max(j0 - 1, 0)];
    d6[rr][5] = dp[min(j0 + 4, WW - 1)];
  }
  const int dy[8] = {1, 1, 1, 0, 0, -1, -1, -1};
  const int dx[8] = {1, 0, -1, 1, -1, 1, 0, -1};
  float g[8][4], dvv[8][4];
#pragma unroll
  for (int k = 0; k < 8; ++k) {
    int y = i + dy[k];
    bool vy = (y >= 0 && y < HH);
    int yc = min(max(y, 0), HH - 1);
    const ushort* ap = aff + ((size_t)(n * 8 + k)) * HW + (size_t)yc * WW;
    float w6[6];
    u16x4 c4 = *(const u16x4*)(ap + j0);
    w6[1] = bf2f(c4[0]); w6[2] = bf2f(c4[1]); w6[3] = bf2f(c4[2]); w6[4] = bf2f(c4[3]);
    w6[0] = bf2f(ap[max(j0 - 1, 0)]);
    w6[5] = bf2f(ap[min(j0 + 4, WW - 1)]);
    int rr = dy[k] + 1;
#pragma unroll
    for (int p = 0; p < 4; ++p) {
      int xp = j0 + p + dx[k];
      bool ok = vy && (xp >= 0) && (xp < WW);
      g[k][p] = ok ? w6[p + 1 + dx[k]] : 0.f;
      dvv[k][p] = ok ? d6[rr][p + 1 + dx[k]] : 0.f;
    }
  }
  float4 res;
#pragma unroll
  for (int p = 0; p < 4; ++p) {
    float m = g[0][p];
#pragma unroll
    for (int k = 1; k < 8; ++k) m = fmaxf(m, g[k][p]);
    float se = 0.f, sed = 0.f;
#pragma unroll
    for (int k = 0; k < 8; ++k) {
      float e = __expf(g[k][p] - m);
      se += e;
      sed += e * dvv[k][p];
    }
    float dc = d6[1][p + 1];
    (&res.x)[p] = 0.3f * (sed / se) + 0.7f * dc;
  }
  *(float4*)(out + (size_t)n * HW + i * WW + j0) = res;
}

extern "C" void kernel_launch(void* const* d_in, const int* in_sizes, int n_in,
                              void* d_out, int out_size, void* d_ws, size_t ws_size,
                              hipStream_t stream) {
  const float* normal = (const float*)d_in[0];
  const float* left   = (const float*)d_in[1];
  const float* right  = (const float*)d_in[2];
  const float* disp   = (const float*)d_in[3];
  const float* w1 = (const float*)d_in[4];
  const float* g1 = (const float*)d_in[5];
  const float* b1 = (const float*)d_in[6];
  const float* m1 = (const float*)d_in[7];
  const float* v1 = (const float*)d_in[8];
  const float* w2 = (const float*)d_in[9];
  const float* g2 = (const float*)d_in[10];
  const float* b2 = (const float*)d_in[11];
  const float* m2 = (const float*)d_in[12];
  const float* v2 = (const float*)d_in[13];
  const float* w3 = (const float*)d_in[14];
  char* wsb  = (char*)d_ws;
  float* out = (float*)d_out;

  hipLaunchKernelGGL(feats_row, dim3(2149), dim3(256), 0, stream,
                     normal, left, right, disp,
                     w1, g1, b1, m1, v1, w2, g2, b2, m2, v2, w3, wsb);
  hipLaunchKernelGGL(trunk_kernel, dim3(2048), dim3(256), 0, stream, wsb);
  hipLaunchKernelGGL(final_kernel, dim3(512), dim3(256), 0, stream, disp, wsb, out);
}